// Round 1
// baseline (1104.611 us; speedup 1.0000x reference)
//
#include <hip/hip_runtime.h>
#include <math.h>

constexpr int B_  = 64;
constexpr int LQ_ = 64;
constexpr int LS_ = 512;
constexpr int S_  = 512;
#define NEGV (-1e6f)

// ---------------- Kernel 1: question attention pooling ----------------
__global__ __launch_bounds__(256)
void qpool_kernel(const float* __restrict__ eq,      // [B,LQ,S]
                  const int*   __restrict__ qlen,    // [B]
                  const float* __restrict__ W_qa,    // [S]
                  float*       __restrict__ q_state) // [B,S]
{
    int b = blockIdx.x;
    int t = threadIdx.x;
    int wave = t >> 6, lane = t & 63;
    __shared__ float att[LQ_];
    __shared__ float wsm[LQ_];
    const float* eqb = eq + (size_t)b * LQ_ * S_;

    // att[q] = dot(eq[b,q,:], W_qa) ; 4 waves x 16 rows
    for (int k = 0; k < 16; ++k) {
        int q = wave + 4 * k;
        const float* row = eqb + q * S_;
        float s = 0.f;
        #pragma unroll
        for (int j = 0; j < S_ / 64; ++j)
            s = fmaf(row[lane + 64 * j], W_qa[lane + 64 * j], s);
        #pragma unroll
        for (int off = 32; off >= 1; off >>= 1)
            s += __shfl_xor(s, off);
        if (lane == 0) att[q] = s;
    }
    __syncthreads();

    // masked softmax over LQ=64 values, done by wave 0
    if (wave == 0) {
        int L = qlen[b];
        float v = att[lane] + ((lane < L) ? 0.f : NEGV);
        float m = v;
        #pragma unroll
        for (int off = 32; off >= 1; off >>= 1)
            m = fmaxf(m, __shfl_xor(m, off));
        float e = expf(v - m);
        float sum = e;
        #pragma unroll
        for (int off = 32; off >= 1; off >>= 1)
            sum += __shfl_xor(sum, off);
        wsm[lane] = e / sum;
    }
    __syncthreads();

    // q_state[b,d] = sum_q wsm[q] * eq[b,q,d]
    for (int d = t; d < S_; d += 256) {
        float acc = 0.f;
        #pragma unroll 8
        for (int q = 0; q < LQ_; ++q)
            acc = fmaf(wsm[q], eqb[q * S_ + d], acc);
        q_state[b * S_ + d] = acc;
    }
}

// ---------------- Kernel 2: q_start_inter / q_end_inter ----------------
__global__ __launch_bounds__(256)
void inter_kernel(const float* __restrict__ q_state,
                  const float* __restrict__ W_qsi, const float* __restrict__ b_qsi,
                  const float* __restrict__ W_qei, const float* __restrict__ b_qei,
                  float* __restrict__ qsi,          // [B,S]
                  float* __restrict__ qei)          // [B,S]
{
    int b = blockIdx.x;
    const float* W  = blockIdx.y ? W_qei : W_qsi;
    const float* bi = blockIdx.y ? b_qei : b_qsi;
    float*       o  = blockIdx.y ? qei   : qsi;
    int t = threadIdx.x;
    __shared__ float qs[S_];
    for (int d = t; d < S_; d += 256) qs[d] = q_state[b * S_ + d];
    __syncthreads();
    for (int s = t; s < S_; s += 256) {
        float acc = bi[s];
        #pragma unroll 8
        for (int d = 0; d < S_; ++d)
            acc = fmaf(qs[d], W[d * S_ + s], acc);
        o[b * S_ + s] = acc;
    }
}

// ---------------- Kernel 3/5: fused score GEMM ----------------
// scores[b,l] = relu( support[b,l,:] @ Wc[b] + inter[b,:] ) . Wsmall  + masks
// Wc built on the fly:
//   START: Wc[d,s] = qs[d]*Wbig[d,s] + Wbig[S+d,s]
//   END:   Wc[d,s] = us[d]*Wbig[d,s] + qs[d]*Wbig[S+d,s] + Wbig[2S+d,s]
template <bool END>
__global__ __launch_bounds__(256)
void score_kernel(const float* __restrict__ support,  // [B,LS,S]
                  const float* __restrict__ q_state,  // [B,S]
                  const float* __restrict__ u_s,      // [B,S] (END only)
                  const float* __restrict__ Wbig,     // [2S,S] or [3S,S]
                  const float* __restrict__ inter,    // [B,S]
                  const float* __restrict__ Wsmall,   // [S]
                  const int*   __restrict__ slen,     // [B]
                  const int*   __restrict__ sp,       // [B] (END only)
                  float*       __restrict__ out)      // [B,LS]
{
    constexpr int TL = 64, TS = 256, TD = 32;
    int b  = blockIdx.y;
    int l0 = blockIdx.x * TL;
    int t  = threadIdx.x;
    int lane = t & 63, wave = t >> 6;
    int rg = t & 7;        // row group: rows rg*8 .. rg*8+7
    int cg = t >> 3;       // col group: cols cg*8 .. cg*8+7 (within 256-chunk)

    __shared__ float sup[TL][TD + 1];      // 8.4 KB
    __shared__ float wc[TD][TS + 4];       // 33.3 KB
    __shared__ float qs_l[S_], wsm_l[S_], int_l[S_], us_l[S_]; // 8 KB
    __shared__ float scoreW[4][TL];        // 1 KB

    for (int i = t; i < S_; i += 256) {
        qs_l[i]  = q_state[b * S_ + i];
        wsm_l[i] = Wsmall[i];
        int_l[i] = inter[b * S_ + i];
        if (END) us_l[i] = u_s[b * S_ + i];
    }
    __syncthreads();

    float partial[8];
    #pragma unroll
    for (int i = 0; i < 8; ++i) partial[i] = 0.f;

    for (int scn = 0; scn < S_ / TS; ++scn) {
        int s0 = scn * TS;
        float acc[8][8];
        #pragma unroll
        for (int i = 0; i < 8; ++i)
            #pragma unroll
            for (int j = 0; j < 8; ++j) acc[i][j] = 0.f;

        for (int dc = 0; dc < S_ / TD; ++dc) {
            int d0 = dc * TD;
            __syncthreads();
            // stage support tile [64 x 32]
            #pragma unroll
            for (int j = 0; j < (TL * TD) / 256; ++j) {
                int idx = t + j * 256;
                int l = idx >> 5, d = idx & 31;
                sup[l][d] = support[((size_t)(b * LS_ + l0 + l)) * S_ + d0 + d];
            }
            // build combined-weight tile [32 x 256]; thread t owns col s0+t
            #pragma unroll
            for (int j = 0; j < TD; ++j) {
                int gd = d0 + j;
                int gs = s0 + t;
                float v;
                if (END) {
                    v = fmaf(us_l[gd], Wbig[(size_t)gd * S_ + gs],
                        fmaf(qs_l[gd], Wbig[(size_t)(S_ + gd) * S_ + gs],
                             Wbig[(size_t)(2 * S_ + gd) * S_ + gs]));
                } else {
                    v = fmaf(qs_l[gd], Wbig[(size_t)gd * S_ + gs],
                             Wbig[(size_t)(S_ + gd) * S_ + gs]);
                }
                wc[j][t] = v;
            }
            __syncthreads();
            // 8x8 register-blocked FMA
            #pragma unroll
            for (int dd = 0; dd < TD; ++dd) {
                float a[8], w[8];
                #pragma unroll
                for (int i = 0; i < 8; ++i) a[i] = sup[rg * 8 + i][dd];
                #pragma unroll
                for (int j = 0; j < 8; ++j) w[j] = wc[dd][cg * 8 + j];
                #pragma unroll
                for (int i = 0; i < 8; ++i)
                    #pragma unroll
                    for (int j = 0; j < 8; ++j)
                        acc[i][j] = fmaf(a[i], w[j], acc[i][j]);
            }
        }
        // epilogue: + inter, relu, dot Wsmall
        #pragma unroll
        for (int i = 0; i < 8; ++i) {
            float p = 0.f;
            #pragma unroll
            for (int j = 0; j < 8; ++j) {
                int s = s0 + cg * 8 + j;
                float v = acc[i][j] + int_l[s];
                v = fmaxf(v, 0.f);
                p = fmaf(v, wsm_l[s], p);
            }
            partial[i] += p;
        }
    }

    // reduce partial over the 8 col-groups within each wave (lanes t^8,t^16,t^32)
    #pragma unroll
    for (int i = 0; i < 8; ++i) {
        float p = partial[i];
        p += __shfl_xor(p, 8);
        p += __shfl_xor(p, 16);
        p += __shfl_xor(p, 32);
        partial[i] = p;
    }
    if (lane < 8) {
        #pragma unroll
        for (int i = 0; i < 8; ++i) scoreW[wave][lane * 8 + i] = partial[i];
    }
    __syncthreads();
    if (t < TL) {
        int l = l0 + t;
        float s = scoreW[0][t] + scoreW[1][t] + scoreW[2][t] + scoreW[3][t];
        if (l >= slen[b]) s += NEGV;
        if (END) { if (l < sp[b]) s += NEGV; }
        out[b * LS_ + l] = s;
    }
}

// ---------------- Kernel 4/6: argmax (+ optional u_s gather) ----------------
__global__ __launch_bounds__(256)
void argmax_kernel(const float* __restrict__ scores,   // [B,LS]
                   const float* __restrict__ support,  // [B,LS,S] or null
                   int*         __restrict__ sp_out,   // [B] or null
                   float*       __restrict__ us_out,   // [B,S] or null
                   float*       __restrict__ pred_out, // [B] (as float)
                   int do_gather)
{
    int b = blockIdx.x;
    int t = threadIdx.x;
    int wave = t >> 6, lane = t & 63;
    __shared__ float bv[4];
    __shared__ int   bi[4];
    __shared__ int   sp_sh;

    float best = -INFINITY;
    int   bidx = 0;
    for (int l = t; l < LS_; l += 256) {     // ascending -> first-max kept
        float v = scores[b * LS_ + l];
        if (v > best) { best = v; bidx = l; }
    }
    #pragma unroll
    for (int off = 32; off >= 1; off >>= 1) {
        float ov = __shfl_xor(best, off);
        int   oi = __shfl_xor(bidx, off);
        if (ov > best || (ov == best && oi < bidx)) { best = ov; bidx = oi; }
    }
    if (lane == 0) { bv[wave] = best; bi[wave] = bidx; }
    __syncthreads();
    if (t == 0) {
        float fb = bv[0]; int fi = bi[0];
        for (int w = 1; w < 4; ++w)
            if (bv[w] > fb || (bv[w] == fb && bi[w] < fi)) { fb = bv[w]; fi = bi[w]; }
        if (sp_out) sp_out[b] = fi;
        pred_out[b] = (float)fi;
        sp_sh = fi;
    }
    __syncthreads();
    if (do_gather) {
        int spv = sp_sh;
        for (int d = t; d < S_; d += 256)
            us_out[b * S_ + d] = support[((size_t)(b * LS_ + spv)) * S_ + d];
    }
}

// ---------------- launch ----------------
extern "C" void kernel_launch(void* const* d_in, const int* in_sizes, int n_in,
                              void* d_out, int out_size, void* d_ws, size_t ws_size,
                              hipStream_t stream)
{
    const float* eq    = (const float*)d_in[0];
    const float* es    = (const float*)d_in[1];
    const int*   qlen  = (const int*)d_in[2];
    const int*   slen  = (const int*)d_in[3];
    // d_in[4] correct_start, d_in[5] answer2question, d_in[6] is_eval: unused (eval path)
    const float* W_qa  = (const float*)d_in[7];
    const float* W_qsi = (const float*)d_in[8];
    const float* b_qsi = (const float*)d_in[9];
    const float* W_qs  = (const float*)d_in[10];
    const float* W_ss  = (const float*)d_in[11];
    const float* W_qei = (const float*)d_in[12];
    const float* b_qei = (const float*)d_in[13];
    const float* W_qe  = (const float*)d_in[14];
    const float* W_es  = (const float*)d_in[15];

    float* out          = (float*)d_out;
    float* start_scores = out;                      // [B,LS]
    float* end_scores   = out + B_ * LS_;           // [B,LS]
    float* pred_start   = out + 2 * B_ * LS_;       // [B]
    float* pred_end     = out + 2 * B_ * LS_ + B_;  // [B]

    float* ws      = (float*)d_ws;
    float* q_state = ws;                  // [B,S]
    float* qsi     = ws + B_ * S_;        // [B,S]
    float* qei     = ws + 2 * B_ * S_;    // [B,S]
    float* u_s     = ws + 3 * B_ * S_;    // [B,S]
    int*   sp_ws   = (int*)(ws + 4 * B_ * S_); // [B]

    qpool_kernel<<<B_, 256, 0, stream>>>(eq, qlen, W_qa, q_state);
    inter_kernel<<<dim3(B_, 2), 256, 0, stream>>>(q_state, W_qsi, b_qsi, W_qei, b_qei, qsi, qei);
    score_kernel<false><<<dim3(LS_ / 64, B_), 256, 0, stream>>>(
        es, q_state, nullptr, W_qs, qsi, W_ss, slen, nullptr, start_scores);
    argmax_kernel<<<B_, 256, 0, stream>>>(start_scores, es, sp_ws, u_s, pred_start, 1);
    score_kernel<true><<<dim3(LS_ / 64, B_), 256, 0, stream>>>(
        es, q_state, u_s, W_qe, qei, W_es, slen, sp_ws, end_scores);
    argmax_kernel<<<B_, 256, 0, stream>>>(end_scores, nullptr, nullptr, nullptr, pred_end, 0);
}

// Round 2
// 329.851 us; speedup vs baseline: 3.3488x; 3.3488x over previous
//
#include <hip/hip_runtime.h>
#include <math.h>

constexpr int B_  = 64;
constexpr int LQ_ = 64;
constexpr int LS_ = 512;
constexpr int S_  = 512;
#define NEGV (-1e6f)

typedef __attribute__((ext_vector_type(8))) short bf16x8;
typedef __attribute__((ext_vector_type(4))) float f32x4;

__device__ inline unsigned short f2bf_rn(float x) {
    unsigned u = __builtin_bit_cast(unsigned, x);
    unsigned r = (u + 0x7FFFu + ((u >> 16) & 1u)) >> 16;
    return (unsigned short)r;
}
__device__ inline float bf2f(unsigned short h) {
    unsigned u = ((unsigned)h) << 16;
    return __builtin_bit_cast(float, u);
}

// ---------------- Kernel 1: question attention pooling ----------------
__global__ __launch_bounds__(256)
void qpool_kernel(const float* __restrict__ eq,      // [B,LQ,S]
                  const int*   __restrict__ qlen,    // [B]
                  const float* __restrict__ W_qa,    // [S]
                  float*       __restrict__ q_state) // [B,S]
{
    int b = blockIdx.x;
    int t = threadIdx.x;
    int wave = t >> 6, lane = t & 63;
    __shared__ float att[LQ_];
    __shared__ float wsm[LQ_];
    const float* eqb = eq + (size_t)b * LQ_ * S_;

    for (int k = 0; k < 16; ++k) {
        int q = wave + 4 * k;
        const float* row = eqb + q * S_;
        float s = 0.f;
        #pragma unroll
        for (int j = 0; j < S_ / 64; ++j)
            s = fmaf(row[lane + 64 * j], W_qa[lane + 64 * j], s);
        #pragma unroll
        for (int off = 32; off >= 1; off >>= 1)
            s += __shfl_xor(s, off);
        if (lane == 0) att[q] = s;
    }
    __syncthreads();

    if (wave == 0) {
        int L = qlen[b];
        float v = att[lane] + ((lane < L) ? 0.f : NEGV);
        float m = v;
        #pragma unroll
        for (int off = 32; off >= 1; off >>= 1)
            m = fmaxf(m, __shfl_xor(m, off));
        float e = expf(v - m);
        float sum = e;
        #pragma unroll
        for (int off = 32; off >= 1; off >>= 1)
            sum += __shfl_xor(sum, off);
        wsm[lane] = e / sum;
    }
    __syncthreads();

    for (int d = t; d < S_; d += 256) {
        float acc = 0.f;
        #pragma unroll 8
        for (int q = 0; q < LQ_; ++q)
            acc = fmaf(wsm[q], eqb[q * S_ + d], acc);
        q_state[b * S_ + d] = acc;
    }
}

// ---------------- Kernel 2: q_start_inter / q_end_inter ----------------
__global__ __launch_bounds__(256)
void inter_kernel(const float* __restrict__ q_state,
                  const float* __restrict__ W_qsi, const float* __restrict__ b_qsi,
                  const float* __restrict__ W_qei, const float* __restrict__ b_qei,
                  float* __restrict__ qsi,          // [B,S]
                  float* __restrict__ qei)          // [B,S]
{
    int b = blockIdx.x;
    const float* W  = blockIdx.y ? W_qei : W_qsi;
    const float* bi = blockIdx.y ? b_qei : b_qsi;
    float*       o  = blockIdx.y ? qei   : qsi;
    int t = threadIdx.x;
    __shared__ float qs[S_];
    for (int d = t; d < S_; d += 256) qs[d] = q_state[b * S_ + d];
    __syncthreads();
    for (int s = t; s < S_; s += 256) {
        float acc = bi[s];
        #pragma unroll 8
        for (int d = 0; d < S_; ++d)
            acc = fmaf(qs[d], W[d * S_ + s], acc);
        o[b * S_ + s] = acc;
    }
}

// ---------------- Kernel 3/5: MFMA score GEMM (split-bf16, 3-term) ----------
// scores[b,l] = relu( support[b,l,:] @ Wc[b] + inter[b,:] ) . Wsmall + masks
//   START: Wc[d,s] = qs[d]*Wbig[d,s] + Wbig[S+d,s]
//   END:   Wc[d,s] = us[d]*Wbig[d,s] + qs[d]*Wbig[S+d,s] + Wbig[2S+d,s]
// Block: 128 l-rows x full 512 s, K-steps of 32.  8 waves (2 wm x 4 wn),
// each wave 64 rows x 128 cols = 4 x 8 frags of 16x16.
template <bool END>
__global__ __launch_bounds__(512)
void score_kernel(const float* __restrict__ support,  // [B,LS,S]
                  const float* __restrict__ q_state,  // [B,S]
                  const float* __restrict__ u_s,      // [B,S] (END only)
                  const float* __restrict__ Wbig,     // [2S,S] or [3S,S]
                  const float* __restrict__ inter,    // [B,S]
                  const float* __restrict__ Wsmall,   // [S]
                  const int*   __restrict__ slen,     // [B]
                  const int*   __restrict__ sp,       // [B] (END only)
                  float*       __restrict__ out)      // [B,LS]
{
    constexpr int BM = 128, KS = 32, STR = 40;   // STR: padded LDS stride (shorts), 80B
    int b  = blockIdx.y;
    int l0 = blockIdx.x * BM;
    int t  = threadIdx.x;
    int lane = t & 63, wid = t >> 6;
    int wm = wid >> 2, wn = wid & 3;
    int l15 = lane & 15, l4 = lane >> 4;

    __shared__ __attribute__((aligned(16))) short As_hi[BM * STR];
    __shared__ __attribute__((aligned(16))) short As_lo[BM * STR];
    __shared__ __attribute__((aligned(16))) short Bs_hi[S_ * STR];
    __shared__ __attribute__((aligned(16))) short Bs_lo[S_ * STR];
    __shared__ float qs_l[S_], int_l[S_], wsm_l[S_], us_l[S_];
    __shared__ float sm_red[BM][4];

    for (int i = t; i < S_; i += 512) {
        qs_l[i]  = q_state[b * S_ + i];
        int_l[i] = inter[b * S_ + i];
        wsm_l[i] = Wsmall[i];
        if (END) us_l[i] = u_s[b * S_ + i];
    }

    f32x4 acc[4][8];
    #pragma unroll
    for (int r = 0; r < 4; ++r)
        #pragma unroll
        for (int c = 0; c < 8; ++c)
            acc[r][c] = (f32x4){0.f, 0.f, 0.f, 0.f};

    for (int ks = 0; ks < S_ / KS; ++ks) {
        int k0 = ks * KS;
        __syncthreads();   // previous compute done before overwriting LDS

        // ---- stage A tile [128 rows x 32 k] as hi/lo bf16 ----
        {
            int r = t >> 2, dc = t & 3;
            const float* src = support + ((size_t)(b * LS_ + l0 + r)) * S_ + k0 + dc * 8;
            float4 f0 = *(const float4*)src;
            float4 f1 = *(const float4*)(src + 4);
            float xs[8] = {f0.x, f0.y, f0.z, f0.w, f1.x, f1.y, f1.z, f1.w};
            bf16x8 vh, vl;
            #pragma unroll
            for (int e = 0; e < 8; ++e) {
                unsigned short h = f2bf_rn(xs[e]);
                float lo = xs[e] - bf2f(h);
                vh[e] = (short)h;
                vl[e] = (short)f2bf_rn(lo);
            }
            *(bf16x8*)&As_hi[r * STR + dc * 8] = vh;
            *(bf16x8*)&As_lo[r * STR + dc * 8] = vl;
        }

        // ---- stage B tile Wc^T [512 s x 32 k] as hi/lo bf16 ----
        #pragma unroll
        for (int dg = 0; dg < 4; ++dg) {
            int s = t;
            bf16x8 vh, vl;
            #pragma unroll
            for (int e = 0; e < 8; ++e) {
                int d = k0 + dg * 8 + e;
                float v;
                if (END) {
                    v = fmaf(us_l[d], Wbig[(size_t)d * S_ + s],
                        fmaf(qs_l[d], Wbig[(size_t)(S_ + d) * S_ + s],
                             Wbig[(size_t)(2 * S_ + d) * S_ + s]));
                } else {
                    v = fmaf(qs_l[d], Wbig[(size_t)d * S_ + s],
                             Wbig[(size_t)(S_ + d) * S_ + s]);
                }
                unsigned short h = f2bf_rn(v);
                float lo = v - bf2f(h);
                vh[e] = (short)h;
                vl[e] = (short)f2bf_rn(lo);
            }
            *(bf16x8*)&Bs_hi[s * STR + dg * 8] = vh;
            *(bf16x8*)&Bs_lo[s * STR + dg * 8] = vl;
        }
        __syncthreads();

        // ---- MFMA: 3-term split ----
        bf16x8 ah[4], al[4];
        #pragma unroll
        for (int r = 0; r < 4; ++r) {
            int row = wm * 64 + r * 16 + l15;
            ah[r] = *(const bf16x8*)&As_hi[row * STR + l4 * 8];
            al[r] = *(const bf16x8*)&As_lo[row * STR + l4 * 8];
        }
        #pragma unroll
        for (int c = 0; c < 8; ++c) {
            int col = wn * 128 + c * 16 + l15;
            bf16x8 bh = *(const bf16x8*)&Bs_hi[col * STR + l4 * 8];
            bf16x8 bl = *(const bf16x8*)&Bs_lo[col * STR + l4 * 8];
            #pragma unroll
            for (int r = 0; r < 4; ++r) {
                acc[r][c] = __builtin_amdgcn_mfma_f32_16x16x32_bf16(ah[r], bh, acc[r][c], 0, 0, 0);
                acc[r][c] = __builtin_amdgcn_mfma_f32_16x16x32_bf16(ah[r], bl, acc[r][c], 0, 0, 0);
                acc[r][c] = __builtin_amdgcn_mfma_f32_16x16x32_bf16(al[r], bh, acc[r][c], 0, 0, 0);
            }
        }
    }

    // ---- epilogue: + inter, relu, dot Wsmall, row-reduce ----
    #pragma unroll
    for (int r = 0; r < 4; ++r) {
        #pragma unroll
        for (int j = 0; j < 4; ++j) {
            float p = 0.f;
            #pragma unroll
            for (int c = 0; c < 8; ++c) {
                int s = wn * 128 + c * 16 + l15;
                float v = acc[r][c][j] + int_l[s];
                v = fmaxf(v, 0.f);
                p = fmaf(v, wsm_l[s], p);
            }
            p += __shfl_xor(p, 1);
            p += __shfl_xor(p, 2);
            p += __shfl_xor(p, 4);
            p += __shfl_xor(p, 8);
            if (l15 == 0) {
                int row = wm * 64 + r * 16 + l4 * 4 + j;
                sm_red[row][wn] = p;
            }
        }
    }
    __syncthreads();
    if (t < BM) {
        int l = l0 + t;
        float s = sm_red[t][0] + sm_red[t][1] + sm_red[t][2] + sm_red[t][3];
        if (l >= slen[b]) s += NEGV;
        if (END) { if (l < sp[b]) s += NEGV; }
        out[b * LS_ + l] = s;
    }
}

// ---------------- Kernel 4/6: argmax (+ optional u_s gather) ----------------
__global__ __launch_bounds__(256)
void argmax_kernel(const float* __restrict__ scores,   // [B,LS]
                   const float* __restrict__ support,  // [B,LS,S] or null
                   int*         __restrict__ sp_out,   // [B] or null
                   float*       __restrict__ us_out,   // [B,S] or null
                   float*       __restrict__ pred_out, // [B] (as float)
                   int do_gather)
{
    int b = blockIdx.x;
    int t = threadIdx.x;
    int wave = t >> 6, lane = t & 63;
    __shared__ float bv[4];
    __shared__ int   bi[4];
    __shared__ int   sp_sh;

    float best = -INFINITY;
    int   bidx = 0;
    for (int l = t; l < LS_; l += 256) {
        float v = scores[b * LS_ + l];
        if (v > best) { best = v; bidx = l; }
    }
    #pragma unroll
    for (int off = 32; off >= 1; off >>= 1) {
        float ov = __shfl_xor(best, off);
        int   oi = __shfl_xor(bidx, off);
        if (ov > best || (ov == best && oi < bidx)) { best = ov; bidx = oi; }
    }
    if (lane == 0) { bv[wave] = best; bi[wave] = bidx; }
    __syncthreads();
    if (t == 0) {
        float fb = bv[0]; int fi = bi[0];
        for (int w = 1; w < 4; ++w)
            if (bv[w] > fb || (bv[w] == fb && bi[w] < fi)) { fb = bv[w]; fi = bi[w]; }
        if (sp_out) sp_out[b] = fi;
        pred_out[b] = (float)fi;
        sp_sh = fi;
    }
    __syncthreads();
    if (do_gather) {
        int spv = sp_sh;
        for (int d = t; d < S_; d += 256)
            us_out[b * S_ + d] = support[((size_t)(b * LS_ + spv)) * S_ + d];
    }
}

// ---------------- launch ----------------
extern "C" void kernel_launch(void* const* d_in, const int* in_sizes, int n_in,
                              void* d_out, int out_size, void* d_ws, size_t ws_size,
                              hipStream_t stream)
{
    const float* eq    = (const float*)d_in[0];
    const float* es    = (const float*)d_in[1];
    const int*   qlen  = (const int*)d_in[2];
    const int*   slen  = (const int*)d_in[3];
    const float* W_qa  = (const float*)d_in[7];
    const float* W_qsi = (const float*)d_in[8];
    const float* b_qsi = (const float*)d_in[9];
    const float* W_qs  = (const float*)d_in[10];
    const float* W_ss  = (const float*)d_in[11];
    const float* W_qei = (const float*)d_in[12];
    const float* b_qei = (const float*)d_in[13];
    const float* W_qe  = (const float*)d_in[14];
    const float* W_es  = (const float*)d_in[15];

    float* out          = (float*)d_out;
    float* start_scores = out;                      // [B,LS]
    float* end_scores   = out + B_ * LS_;           // [B,LS]
    float* pred_start   = out + 2 * B_ * LS_;       // [B]
    float* pred_end     = out + 2 * B_ * LS_ + B_;  // [B]

    float* ws      = (float*)d_ws;
    float* q_state = ws;                  // [B,S]
    float* qsi     = ws + B_ * S_;        // [B,S]
    float* qei     = ws + 2 * B_ * S_;    // [B,S]
    float* u_s     = ws + 3 * B_ * S_;    // [B,S]
    int*   sp_ws   = (int*)(ws + 4 * B_ * S_); // [B]

    qpool_kernel<<<B_, 256, 0, stream>>>(eq, qlen, W_qa, q_state);
    inter_kernel<<<dim3(B_, 2), 256, 0, stream>>>(q_state, W_qsi, b_qsi, W_qei, b_qei, qsi, qei);
    score_kernel<false><<<dim3(LS_ / 128, B_), 512, 0, stream>>>(
        es, q_state, nullptr, W_qs, qsi, W_ss, slen, nullptr, start_scores);
    argmax_kernel<<<B_, 256, 0, stream>>>(start_scores, es, sp_ws, u_s, pred_start, 1);
    score_kernel<true><<<dim3(LS_ / 128, B_), 512, 0, stream>>>(
        es, q_state, u_s, W_qe, qei, W_es, slen, sp_ws, end_scores);
    argmax_kernel<<<B_, 256, 0, stream>>>(end_scores, nullptr, nullptr, nullptr, pred_end, 0);
}

// Round 4
// 288.555 us; speedup vs baseline: 3.8281x; 1.1431x over previous
//
#include <hip/hip_runtime.h>
#include <math.h>

constexpr int B_  = 64;
constexpr int LQ_ = 64;
constexpr int LS_ = 512;
constexpr int S_  = 512;
#define NEGV (-1e6f)

typedef __attribute__((ext_vector_type(8))) short bf16x8;
typedef __attribute__((ext_vector_type(4))) float f32x4;

__device__ inline unsigned short f2bf_rn(float x) {
    unsigned u = __builtin_bit_cast(unsigned, x);
    unsigned r = (u + 0x7FFFu + ((u >> 16) & 1u)) >> 16;
    return (unsigned short)r;
}
__device__ inline float bf2f(unsigned short h) {
    unsigned u = ((unsigned)h) << 16;
    return __builtin_bit_cast(float, u);
}
__device__ inline unsigned pack2bf(float a, float b) {
    // low short = trunc-bf16(a), high short = trunc-bf16(b)
    return (__builtin_bit_cast(unsigned, a) >> 16) |
           (__builtin_bit_cast(unsigned, b) & 0xFFFF0000u);
}
__device__ inline float hi_part(float x) {
    return __builtin_bit_cast(float, __builtin_bit_cast(unsigned, x) & 0xFFFF0000u);
}

// ---------------- Kernel 0: pre-swizzled hi/lo bf16 weight prep ----------------
// Layout: per sub-iter j (j = i*NW + w; contraction rows D = w*512 + i*32 + k):
//   chunk (col, c) of 8 shorts at short-offset j*32768 + col*64 + (c ^ (col&7))*8
//   c = kchunk (0..3) for hi, 4|kchunk for lo.  RN split (one-time prep).
template <int NW>
__global__ __launch_bounds__(256)
void prepB_kernel(const float* __restrict__ W,   // [NW*S, S]
                  short*       __restrict__ out)
{
    int g   = blockIdx.x * 256 + threadIdx.x;    // < NW*16*512*4
    int kc  = g & 3;
    int col = (g >> 2) & 511;
    int j   = g >> 11;
    int w   = j % NW, i = j / NW;
    int Dbase = w * 512 + i * 32 + kc * 8;

    unsigned short hs[8], ls[8];
    #pragma unroll
    for (int e = 0; e < 8; ++e) {
        float x = W[(size_t)(Dbase + e) * S_ + col];
        unsigned short h = f2bf_rn(x);
        float lo = x - bf2f(h);
        hs[e] = h;
        ls[e] = f2bf_rn(lo);
    }
    uint4 H, L;
    H.x = hs[0] | ((unsigned)hs[1] << 16); H.y = hs[2] | ((unsigned)hs[3] << 16);
    H.z = hs[4] | ((unsigned)hs[5] << 16); H.w = hs[6] | ((unsigned)hs[7] << 16);
    L.x = ls[0] | ((unsigned)ls[1] << 16); L.y = ls[2] | ((unsigned)ls[3] << 16);
    L.z = ls[4] | ((unsigned)ls[5] << 16); L.w = ls[6] | ((unsigned)ls[7] << 16);

    size_t ob = (size_t)j * 32768 + (size_t)col * 64;
    int sl_hi = kc ^ (col & 7);
    int sl_lo = (4 | kc) ^ (col & 7);
    *(uint4*)&out[ob + sl_hi * 8] = H;
    *(uint4*)&out[ob + sl_lo * 8] = L;
}

// ---------------- Kernel 1: question attention pooling ----------------
__global__ __launch_bounds__(256)
void qpool_kernel(const float* __restrict__ eq,      // [B,LQ,S]
                  const int*   __restrict__ qlen,    // [B]
                  const float* __restrict__ W_qa,    // [S]
                  float*       __restrict__ q_state) // [B,S]
{
    int b = blockIdx.x;
    int t = threadIdx.x;
    int wave = t >> 6, lane = t & 63;
    __shared__ float att[LQ_];
    __shared__ float wsm[LQ_];
    const float* eqb = eq + (size_t)b * LQ_ * S_;

    for (int k = 0; k < 16; ++k) {
        int q = wave + 4 * k;
        const float* row = eqb + q * S_;
        float s = 0.f;
        #pragma unroll
        for (int j = 0; j < S_ / 64; ++j)
            s = fmaf(row[lane + 64 * j], W_qa[lane + 64 * j], s);
        #pragma unroll
        for (int off = 32; off >= 1; off >>= 1)
            s += __shfl_xor(s, off);
        if (lane == 0) att[q] = s;
    }
    __syncthreads();

    if (wave == 0) {
        int L = qlen[b];
        float v = att[lane] + ((lane < L) ? 0.f : NEGV);
        float m = v;
        #pragma unroll
        for (int off = 32; off >= 1; off >>= 1)
            m = fmaxf(m, __shfl_xor(m, off));
        float e = expf(v - m);
        float sum = e;
        #pragma unroll
        for (int off = 32; off >= 1; off >>= 1)
            sum += __shfl_xor(sum, off);
        wsm[lane] = e / sum;
    }
    __syncthreads();

    for (int d = t; d < S_; d += 256) {
        float acc = 0.f;
        #pragma unroll 8
        for (int q = 0; q < LQ_; ++q)
            acc = fmaf(wsm[q], eqb[q * S_ + d], acc);
        q_state[b * S_ + d] = acc;
    }
}

// ---------------- Kernel 2: q_start_inter / q_end_inter ----------------
__global__ __launch_bounds__(256)
void inter_kernel(const float* __restrict__ q_state,
                  const float* __restrict__ W_qsi, const float* __restrict__ b_qsi,
                  const float* __restrict__ W_qei, const float* __restrict__ b_qei,
                  float* __restrict__ qsi,          // [B,S]
                  float* __restrict__ qei)          // [B,S]
{
    int b = blockIdx.x;
    const float* W  = blockIdx.y ? W_qei : W_qsi;
    const float* bi = blockIdx.y ? b_qei : b_qsi;
    float*       o  = blockIdx.y ? qei   : qsi;
    int t = threadIdx.x;
    __shared__ float qs[S_];
    for (int d = t; d < S_; d += 256) qs[d] = q_state[b * S_ + d];
    __syncthreads();
    for (int s = t; s < S_; s += 256) {
        float acc = bi[s];
        #pragma unroll 8
        for (int d = 0; d < S_; ++d)
            acc = fmaf(qs[d], W[d * S_ + s], acc);
        o[b * S_ + s] = acc;
    }
}

// ---------------- Kernel 3/5: MFMA score GEMM, unfolded K', prepped B ----------
// H[l,s] = sum_w (A ⊙ scale_w)[l,:] @ W_w  ;  scores = relu(H + inter) . Wsmall
// NW=2 (start): scales {qs, 1} ; NW=3 (end): scales {us, qs, 1}
template <int NW>
__global__ __launch_bounds__(512)
void score_kernel(const float* __restrict__ support,  // [B,LS,S]
                  const float* __restrict__ q_state,  // [B,S]
                  const float* __restrict__ u_s,      // [B,S] (NW==3)
                  const short* __restrict__ Bprep,    // prepped weights
                  const float* __restrict__ inter,    // [B,S]
                  const float* __restrict__ Wsmall,   // [S]
                  const int*   __restrict__ slen,     // [B]
                  const int*   __restrict__ sp,       // [B] (NW==3)
                  float*       __restrict__ out)      // [B,LS]
{
    const int t = threadIdx.x;
    const int lane = t & 63, wid = t >> 6;
    const int wm = wid >> 2, wn = wid & 3;
    const int l15 = lane & 15, l4 = lane >> 4;

    // XCD-grouped remap: 4 blocks of a batch land on one XCD (shared L2)
    int lid  = blockIdx.y * gridDim.x + blockIdx.x;   // gridDim.x == 4
    int xcd  = lid & 7, slot = lid >> 3;
    int b    = xcd * 8 + (slot >> 2);
    int l0   = (slot & 3) * 128;

    // LDS: B double-buffer 128KB + A 16KB + scalars
    __shared__ __attribute__((aligned(16))) short Bs[2 * 512 * 64]; // 128 KB
    __shared__ __attribute__((aligned(16))) short As[128 * 64];     // 16 KB
    __shared__ float qs_l[S_], us_l[S_], int_l[S_], wsm_l[S_];
    __shared__ float sm_red[128][4];

    for (int i2 = t; i2 < S_; i2 += 512) {
        qs_l[i2]  = q_state[b * S_ + i2];
        int_l[i2] = inter[b * S_ + i2];
        wsm_l[i2] = Wsmall[i2];
        us_l[i2]  = (NW == 3) ? u_s[b * S_ + i2] : 0.f;
    }
    __syncthreads();

    f32x4 acc[4][8];
    #pragma unroll
    for (int r = 0; r < 4; ++r)
        #pragma unroll
        for (int c = 0; c < 8; ++c)
            acc[r][c] = (f32x4){0.f, 0.f, 0.f, 0.f};

    const int J = NW * 16;
    const int arow = t >> 2, akc = t & 3;

    // stage B(0) into buffer 0: one tile = 64 KB = 512 thr x 16 B x 8 chunks
    {
        const char* gb = (const char*)Bprep + (size_t)t * 16;
        char* lb = ((char*)Bs) + (wid << 10);
        #pragma unroll
        for (int q = 0; q < 8; ++q)
            __builtin_amdgcn_global_load_lds(
                (const __attribute__((address_space(1))) void*)(gb + q * 8192),
                (__attribute__((address_space(3))) void*)(lb + q * 8192), 16, 0, 0);
    }

    float4 sv0, sv1;
    for (int j = 0; j < J; ++j) {
        const int p = j & 1;
        const int w = j % NW;
        const int i = j / NW;

        // support regs for this K-tile
        if (w == 0) {
            const float* sptr = support + ((size_t)(b * LS_ + l0 + arow)) * S_ + i * 32 + akc * 8;
            sv0 = *(const float4*)sptr;
            sv1 = *(const float4*)(sptr + 4);
        }

        // prefetch B(j+1) into the other buffer (8 x 16B per thread = 64 KB)
        if (j + 1 < J) {
            const char* gb = (const char*)Bprep + (size_t)(j + 1) * 65536 + (size_t)t * 16;
            char* lb = ((char*)Bs) + (p ^ 1) * 65536 + (wid << 10);
            #pragma unroll
            for (int q = 0; q < 8; ++q)
                __builtin_amdgcn_global_load_lds(
                    (const __attribute__((address_space(1))) void*)(gb + q * 8192),
                    (__attribute__((address_space(3))) void*)(lb + q * 8192), 16, 0, 0);
        }

        // build A window w: scale support regs, trunc-split hi/lo, ds_write
        {
            float x[8] = {sv0.x, sv0.y, sv0.z, sv0.w, sv1.x, sv1.y, sv1.z, sv1.w};
            float y[8];
            #pragma unroll
            for (int e = 0; e < 8; ++e) {
                int d = i * 32 + akc * 8 + e;
                float s;
                if (NW == 2) s = (w == 0) ? qs_l[d] : 1.f;
                else         s = (w == 0) ? us_l[d] : ((w == 1) ? qs_l[d] : 1.f);
                y[e] = x[e] * s;
            }
            uint4 H, L;
            float lo[8];
            #pragma unroll
            for (int e = 0; e < 8; ++e) lo[e] = y[e] - hi_part(y[e]);
            H.x = pack2bf(y[0], y[1]); H.y = pack2bf(y[2], y[3]);
            H.z = pack2bf(y[4], y[5]); H.w = pack2bf(y[6], y[7]);
            L.x = pack2bf(lo[0], lo[1]); L.y = pack2bf(lo[2], lo[3]);
            L.z = pack2bf(lo[4], lo[5]); L.w = pack2bf(lo[6], lo[7]);
            int sl_hi = akc ^ (arow & 7);
            int sl_lo = (4 | akc) ^ (arow & 7);
            *(uint4*)&As[arow * 64 + sl_hi * 8] = H;
            *(uint4*)&As[arow * 64 + sl_lo * 8] = L;
        }

        // B(j) landed (8 newer prefetch loads may stay in flight); A writes done
        if (j + 1 < J) asm volatile("s_waitcnt vmcnt(8) lgkmcnt(0)" ::: "memory");
        else           asm volatile("s_waitcnt vmcnt(0) lgkmcnt(0)" ::: "memory");
        __builtin_amdgcn_s_barrier();

        // fragments + MFMA (3-term split)
        bf16x8 ah[4], al[4];
        #pragma unroll
        for (int r = 0; r < 4; ++r) {
            int row = wm * 64 + r * 16 + l15;
            ah[r] = *(const bf16x8*)&As[row * 64 + ((l4 ^ (row & 7)) * 8)];
            al[r] = *(const bf16x8*)&As[row * 64 + ((((4 | l4)) ^ (row & 7)) * 8)];
        }
        const short* Bb = Bs + p * 32768;
        #pragma unroll
        for (int c = 0; c < 8; ++c) {
            int col = wn * 128 + c * 16 + l15;
            bf16x8 bh = *(const bf16x8*)&Bb[col * 64 + ((l4 ^ (col & 7)) * 8)];
            bf16x8 bl = *(const bf16x8*)&Bb[col * 64 + ((((4 | l4)) ^ (col & 7)) * 8)];
            #pragma unroll
            for (int r = 0; r < 4; ++r) {
                acc[r][c] = __builtin_amdgcn_mfma_f32_16x16x32_bf16(ah[r], bh, acc[r][c], 0, 0, 0);
                acc[r][c] = __builtin_amdgcn_mfma_f32_16x16x32_bf16(ah[r], bl, acc[r][c], 0, 0, 0);
                acc[r][c] = __builtin_amdgcn_mfma_f32_16x16x32_bf16(al[r], bh, acc[r][c], 0, 0, 0);
            }
        }
        asm volatile("s_waitcnt lgkmcnt(0)" ::: "memory");
        __builtin_amdgcn_s_barrier();
    }

    // ---- epilogue: + inter, relu, dot Wsmall, row-reduce ----
    #pragma unroll
    for (int r = 0; r < 4; ++r) {
        #pragma unroll
        for (int jj = 0; jj < 4; ++jj) {
            float pr = 0.f;
            #pragma unroll
            for (int c = 0; c < 8; ++c) {
                int s = wn * 128 + c * 16 + l15;
                float v = acc[r][c][jj] + int_l[s];
                v = fmaxf(v, 0.f);
                pr = fmaf(v, wsm_l[s], pr);
            }
            pr += __shfl_xor(pr, 1);
            pr += __shfl_xor(pr, 2);
            pr += __shfl_xor(pr, 4);
            pr += __shfl_xor(pr, 8);
            if (l15 == 0) {
                int row = wm * 64 + r * 16 + l4 * 4 + jj;
                sm_red[row][wn] = pr;
            }
        }
    }
    __syncthreads();
    if (t < 128) {
        int l = l0 + t;
        float s = sm_red[t][0] + sm_red[t][1] + sm_red[t][2] + sm_red[t][3];
        if (l >= slen[b]) s += NEGV;
        if (NW == 3) { if (l < sp[b]) s += NEGV; }
        out[b * LS_ + l] = s;
    }
}

// ---------------- Kernel 4/6: argmax (+ optional u_s gather) ----------------
__global__ __launch_bounds__(256)
void argmax_kernel(const float* __restrict__ scores,   // [B,LS]
                   const float* __restrict__ support,  // [B,LS,S] or null
                   int*         __restrict__ sp_out,   // [B] or null
                   float*       __restrict__ us_out,   // [B,S] or null
                   float*       __restrict__ pred_out, // [B] (as float)
                   int do_gather)
{
    int b = blockIdx.x;
    int t = threadIdx.x;
    int wave = t >> 6, lane = t & 63;
    __shared__ float bv[4];
    __shared__ int   bi[4];
    __shared__ int   sp_sh;

    float best = -INFINITY;
    int   bidx = 0;
    for (int l = t; l < LS_; l += 256) {
        float v = scores[b * LS_ + l];
        if (v > best) { best = v; bidx = l; }
    }
    #pragma unroll
    for (int off = 32; off >= 1; off >>= 1) {
        float ov = __shfl_xor(best, off);
        int   oi = __shfl_xor(bidx, off);
        if (ov > best || (ov == best && oi < bidx)) { best = ov; bidx = oi; }
    }
    if (lane == 0) { bv[wave] = best; bi[wave] = bidx; }
    __syncthreads();
    if (t == 0) {
        float fb = bv[0]; int fi = bi[0];
        for (int w = 1; w < 4; ++w)
            if (bv[w] > fb || (bv[w] == fb && bi[w] < fi)) { fb = bv[w]; fi = bi[w]; }
        if (sp_out) sp_out[b] = fi;
        pred_out[b] = (float)fi;
        sp_sh = fi;
    }
    __syncthreads();
    if (do_gather) {
        int spv = sp_sh;
        for (int d = t; d < S_; d += 256)
            us_out[b * S_ + d] = support[((size_t)(b * LS_ + spv)) * S_ + d];
    }
}

// ---------------- launch ----------------
extern "C" void kernel_launch(void* const* d_in, const int* in_sizes, int n_in,
                              void* d_out, int out_size, void* d_ws, size_t ws_size,
                              hipStream_t stream)
{
    const float* eq    = (const float*)d_in[0];
    const float* es    = (const float*)d_in[1];
    const int*   qlen  = (const int*)d_in[2];
    const int*   slen  = (const int*)d_in[3];
    const float* W_qa  = (const float*)d_in[7];
    const float* W_qsi = (const float*)d_in[8];
    const float* b_qsi = (const float*)d_in[9];
    const float* W_qs  = (const float*)d_in[10];
    const float* W_ss  = (const float*)d_in[11];
    const float* W_qei = (const float*)d_in[12];
    const float* b_qei = (const float*)d_in[13];
    const float* W_qe  = (const float*)d_in[14];
    const float* W_es  = (const float*)d_in[15];

    float* out          = (float*)d_out;
    float* start_scores = out;                      // [B,LS]
    float* end_scores   = out + B_ * LS_;           // [B,LS]
    float* pred_start   = out + 2 * B_ * LS_;       // [B]
    float* pred_end     = out + 2 * B_ * LS_ + B_;  // [B]

    float* ws      = (float*)d_ws;
    float* q_state = ws;                  // [B,S]
    float* qsi     = ws + B_ * S_;        // [B,S]
    float* qei     = ws + 2 * B_ * S_;    // [B,S]
    float* u_s     = ws + 3 * B_ * S_;    // [B,S]
    int*   sp_ws   = (int*)(ws + 4 * B_ * S_);          // [B]
    short* Bstart  = (short*)(ws + 4 * B_ * S_ + 64);   // 2*16*32768 shorts = 2 MB
    short* Bend    = Bstart + 2 * 16 * 32768;           // 3*16*32768 shorts = 3 MB

    prepB_kernel<2><<<256, 256, 0, stream>>>(W_qs, Bstart);
    prepB_kernel<3><<<384, 256, 0, stream>>>(W_qe, Bend);
    qpool_kernel<<<B_, 256, 0, stream>>>(eq, qlen, W_qa, q_state);
    inter_kernel<<<dim3(B_, 2), 256, 0, stream>>>(q_state, W_qsi, b_qsi, W_qei, b_qei, qsi, qei);
    score_kernel<2><<<dim3(4, B_), 512, 0, stream>>>(
        es, q_state, nullptr, Bstart, qsi, W_ss, slen, nullptr, start_scores);
    argmax_kernel<<<B_, 256, 0, stream>>>(start_scores, es, sp_ws, u_s, pred_start, 1);
    score_kernel<3><<<dim3(4, B_), 512, 0, stream>>>(
        es, q_state, u_s, Bend, qei, W_es, slen, sp_ws, end_scores);
    argmax_kernel<<<B_, 256, 0, stream>>>(end_scores, nullptr, nullptr, nullptr, pred_end, 0);
}

// Round 5
// 254.332 us; speedup vs baseline: 4.3432x; 1.1346x over previous
//
#include <hip/hip_runtime.h>
#include <math.h>

constexpr int B_  = 64;
constexpr int LQ_ = 64;
constexpr int LS_ = 512;
constexpr int S_  = 512;
#define NEGV (-1e6f)
#define MARGIN 0.0625f

typedef __attribute__((ext_vector_type(8))) short bf16x8;
typedef __attribute__((ext_vector_type(4))) float f32x4;

__device__ inline unsigned short f2bf_rn(float x) {
    unsigned u = __builtin_bit_cast(unsigned, x);
    unsigned r = (u + 0x7FFFu + ((u >> 16) & 1u)) >> 16;
    return (unsigned short)r;
}

// ---------------- Kernel 1: question attention pooling ----------------
__global__ __launch_bounds__(256)
void qpool_kernel(const float* __restrict__ eq, const int* __restrict__ qlen,
                  const float* __restrict__ W_qa, float* __restrict__ q_state)
{
    int b = blockIdx.x;
    int t = threadIdx.x;
    int wave = t >> 6, lane = t & 63;
    __shared__ float att[LQ_];
    __shared__ float wsm[LQ_];
    const float* eqb = eq + (size_t)b * LQ_ * S_;

    for (int k = 0; k < 16; ++k) {
        int q = wave + 4 * k;
        const float* row = eqb + q * S_;
        float s = 0.f;
        #pragma unroll
        for (int j = 0; j < S_ / 64; ++j)
            s = fmaf(row[lane + 64 * j], W_qa[lane + 64 * j], s);
        #pragma unroll
        for (int off = 32; off >= 1; off >>= 1)
            s += __shfl_xor(s, off);
        if (lane == 0) att[q] = s;
    }
    __syncthreads();

    if (wave == 0) {
        int L = qlen[b];
        float v = att[lane] + ((lane < L) ? 0.f : NEGV);
        float m = v;
        #pragma unroll
        for (int off = 32; off >= 1; off >>= 1)
            m = fmaxf(m, __shfl_xor(m, off));
        float e = expf(v - m);
        float sum = e;
        #pragma unroll
        for (int off = 32; off >= 1; off >>= 1)
            sum += __shfl_xor(sum, off);
        wsm[lane] = e / sum;
    }
    __syncthreads();

    for (int d = t; d < S_; d += 256) {
        float acc = 0.f;
        #pragma unroll 8
        for (int q = 0; q < LQ_; ++q)
            acc = fmaf(wsm[q], eqb[q * S_ + d], acc);
        q_state[b * S_ + d] = acc;
    }
}

// ---------------- Kernel 2: q_start_inter / q_end_inter (f32 exact) --------
__global__ __launch_bounds__(256)
void inter_kernel(const float* __restrict__ q_state,
                  const float* __restrict__ W_qsi, const float* __restrict__ b_qsi,
                  const float* __restrict__ W_qei, const float* __restrict__ b_qei,
                  float* __restrict__ qsi, float* __restrict__ qei)
{
    int b = blockIdx.x;
    const float* W  = blockIdx.y ? W_qei : W_qsi;
    const float* bi = blockIdx.y ? b_qei : b_qsi;
    float*       o  = blockIdx.y ? qei   : qsi;
    int t = threadIdx.x;
    __shared__ float qs[S_];
    for (int d = t; d < S_; d += 256) qs[d] = q_state[b * S_ + d];
    __syncthreads();
    for (int s = t; s < S_; s += 256) {
        float acc = bi[s];
        #pragma unroll 8
        for (int d = 0; d < S_; ++d)
            acc = fmaf(qs[d], W[d * S_ + s], acc);
        o[b * S_ + s] = acc;
    }
}

// ---------------- Kernel P: per-batch folded weight prep (bf16 hi) ---------
// Wc[b][i][kc][col][e] shorts; D = i*32 + kc*8 + e.
// NT=2: Wc = qs[D]*W[D,col] + W[512+D,col]
// NT=3: Wc = us[D]*W[D,col] + qs[D]*W[512+D,col] + W[1024+D,col]
template <int NT>
__global__ __launch_bounds__(512)
void prep_kernel(const float* __restrict__ W, const float* __restrict__ q_state,
                 const float* __restrict__ u_s, short* __restrict__ Wc)
{
    int bid = blockIdx.x;
    int i = bid >> 6, b = bid & 63;     // 64 consecutive blocks share W slice (L2)
    int col = threadIdx.x;
    __shared__ float scq[32], scu[32];
    if (col < 32) scq[col] = q_state[b * S_ + i * 32 + col];
    if (NT == 3 && col >= 32 && col < 64) scu[col - 32] = u_s[b * S_ + i * 32 + col - 32];
    __syncthreads();

    unsigned short h[32];
    #pragma unroll
    for (int d = 0; d < 32; ++d) {
        int D = i * 32 + d;
        float v;
        if (NT == 2)
            v = fmaf(scq[d], W[(size_t)D * S_ + col], W[(size_t)(S_ + D) * S_ + col]);
        else
            v = fmaf(scu[d], W[(size_t)D * S_ + col],
                fmaf(scq[d], W[(size_t)(S_ + D) * S_ + col], W[(size_t)(2 * S_ + D) * S_ + col]));
        h[d] = f2bf_rn(v);
    }
    size_t base = (size_t)b * 262144 + (size_t)i * 16384 + (size_t)col * 8;
    #pragma unroll
    for (int kc = 0; kc < 4; ++kc) {
        uint4 H;
        H.x = h[kc*8+0] | ((unsigned)h[kc*8+1] << 16);
        H.y = h[kc*8+2] | ((unsigned)h[kc*8+3] << 16);
        H.z = h[kc*8+4] | ((unsigned)h[kc*8+5] << 16);
        H.w = h[kc*8+6] | ((unsigned)h[kc*8+7] << 16);
        *(uint4*)&Wc[base + kc * 4096] = H;
    }
}

// ---------------- Kernel S: folded 1-term bf16 MFMA score ----------------
// H[l,s] = A[l,:] @ Wc[b]; scores = relu(H + inter) . Wsmall + masks
// Block: 64 rows x 512 cols, 8 waves (1x8), K-step 32, 2 blocks/CU.
template <bool END>
__global__ __launch_bounds__(512, 4)
void score_kernel(const float* __restrict__ support, const short* __restrict__ Wc,
                  const float* __restrict__ inter, const float* __restrict__ Wsmall,
                  const int* __restrict__ slen, const int* __restrict__ sp,
                  float* __restrict__ out)
{
    const int t = threadIdx.x;
    const int lane = t & 63, wid = t >> 6;
    const int l15 = lane & 15, l4 = lane >> 4;

    // XCD-grouped: batches b=xcd*8..xcd*8+7 live on one XCD (Wc L2-resident)
    int L = blockIdx.x;
    int xcd = L & 7, idx = L >> 3;
    int b = xcd * 8 + (idx & 7);
    int rc = idx >> 3;
    int l0 = rc * 64;

    __shared__ __attribute__((aligned(16))) short Bs[2][4][512][8];  // 64 KB
    __shared__ __attribute__((aligned(16))) short As[2][4][64][8];   // 8 KB
    __shared__ float int_l[S_], wsm_l[S_];
    __shared__ float sm_red[64][8];

    int_l[t] = inter[b * S_ + t];
    wsm_l[t] = Wsmall[t];

    const char* wc_bytes = (const char*)(Wc + (size_t)b * 262144);

    const int arow = t >> 3;
    const int akc  = (t >> 1) & 3;
    const int ahalf = t & 1;
    const float* supb = support + ((size_t)(b * LS_ + l0 + arow)) * S_ + akc * 8 + ahalf * 4;

    f32x4 acc[4][4];
    #pragma unroll
    for (int r = 0; r < 4; ++r)
        #pragma unroll
        for (int c = 0; c < 4; ++c)
            acc[r][c] = (f32x4){0.f, 0.f, 0.f, 0.f};

    auto stage = [&](int i, int pbuf) {
        const char* gb = wc_bytes + (size_t)i * 32768 + t * 16;
        char* lb = (char*)&Bs[pbuf][0][0][0] + t * 16;
        #pragma unroll
        for (int q = 0; q < 4; ++q)
            __builtin_amdgcn_global_load_lds(
                (const __attribute__((address_space(1))) void*)(gb + q * 8192),
                (__attribute__((address_space(3))) void*)(lb + q * 8192), 16, 0, 0);
    };
    auto buildA = [&](int pbuf, float4 v) {
        unsigned short h0 = f2bf_rn(v.x), h1 = f2bf_rn(v.y);
        unsigned short h2 = f2bf_rn(v.z), h3 = f2bf_rn(v.w);
        uint2 P;
        P.x = h0 | ((unsigned)h1 << 16);
        P.y = h2 | ((unsigned)h3 << 16);
        *(uint2*)&As[pbuf][akc][arow][ahalf * 4] = P;
    };

    // prologue
    float4 sv = *(const float4*)(supb);
    buildA(0, sv);
    stage(0, 0);
    float4 svn = *(const float4*)(supb + 32);

    for (int i = 0; i < 16; ++i) {
        const int par = i & 1;
        if (i + 1 < 16) {
            stage(i + 1, par ^ 1);
            buildA(par ^ 1, svn);          // implicit vmcnt wait drains B(i)
            if (i + 2 < 16) svn = *(const float4*)(supb + (i + 2) * 32);
            asm volatile("s_waitcnt vmcnt(5) lgkmcnt(0)" ::: "memory");
        } else {
            asm volatile("s_waitcnt vmcnt(0) lgkmcnt(0)" ::: "memory");
        }
        __builtin_amdgcn_s_barrier();

        bf16x8 ah[4];
        #pragma unroll
        for (int r = 0; r < 4; ++r)
            ah[r] = *(const bf16x8*)&As[par][l4][r * 16 + l15][0];
        #pragma unroll
        for (int c = 0; c < 4; ++c) {
            bf16x8 bh = *(const bf16x8*)&Bs[par][l4][wid * 64 + c * 16 + l15][0];
            #pragma unroll
            for (int r = 0; r < 4; ++r)
                acc[r][c] = __builtin_amdgcn_mfma_f32_16x16x32_bf16(ah[r], bh, acc[r][c], 0, 0, 0);
        }
        asm volatile("s_waitcnt lgkmcnt(0)" ::: "memory");
        __builtin_amdgcn_s_barrier();
    }

    // epilogue: + inter, relu, dot Wsmall, row-reduce
    #pragma unroll
    for (int r = 0; r < 4; ++r) {
        #pragma unroll
        for (int jj = 0; jj < 4; ++jj) {
            float pr = 0.f;
            #pragma unroll
            for (int c = 0; c < 4; ++c) {
                int col = wid * 64 + c * 16 + l15;
                float v = acc[r][c][jj] + int_l[col];
                v = fmaxf(v, 0.f);
                pr = fmaf(v, wsm_l[col], pr);
            }
            pr += __shfl_xor(pr, 1);
            pr += __shfl_xor(pr, 2);
            pr += __shfl_xor(pr, 4);
            pr += __shfl_xor(pr, 8);
            if (l15 == 0) sm_red[r * 16 + l4 * 4 + jj][wid] = pr;
        }
    }
    __syncthreads();
    if (t < 64) {
        int l = l0 + t;
        float s = 0.f;
        #pragma unroll
        for (int w = 0; w < 8; ++w) s += sm_red[t][w];
        if (l >= slen[b]) s += NEGV;
        if (END) { if (l < sp[b]) s += NEGV; }
        out[b * LS_ + l] = s;
    }
}

// ---------------- candidate selection (shared by rescue/finalize) ----------
// returns count (<=8); cand[] ascending indices of scores >= max - MARGIN
__device__ inline int select_cands(const float* s_l, int t, int lane, int w,
                                   float* wred, int* wcnt, int* cand)
{
    float v = s_l[t];
    #pragma unroll
    for (int off = 32; off >= 1; off >>= 1)
        v = fmaxf(v, __shfl_xor(v, off));
    if (lane == 0) wred[w] = v;
    __syncthreads();
    float m = wred[0];
    #pragma unroll
    for (int k = 1; k < 8; ++k) m = fmaxf(m, wred[k]);
    float th = m - MARGIN;
    bool flag = s_l[t] >= th;
    unsigned long long bal = __ballot(flag);
    int rank = __popcll(bal & ((1ull << lane) - 1ull));
    if (lane == 0) wcnt[w] = (int)__popcll(bal);
    __syncthreads();
    int off = 0, total = 0;
    #pragma unroll
    for (int k = 0; k < 8; ++k) { if (k < w) off += wcnt[k]; total += wcnt[k]; }
    if (flag) { int pos = off + rank; if (pos < 8) cand[pos] = t; }
    __syncthreads();
    return total < 8 ? total : 8;
}

// ---------------- Kernel R: exact f32 rescue (partial sums per s-chunk) ----
template <bool END>
__global__ __launch_bounds__(512)
void rescue_kernel(const float* __restrict__ support, const float* __restrict__ q_state,
                   const float* __restrict__ u_s, const float* __restrict__ Wbig,
                   const float* __restrict__ inter, const float* __restrict__ Wsmall,
                   const float* __restrict__ scores, float* __restrict__ part)
{
    int bid = blockIdx.x;
    int b = bid >> 2, chunk = bid & 3;
    int t = threadIdx.x, lane = t & 63, w = t >> 6;
    __shared__ float s_l[S_], qs_l[S_], us_l[S_];
    __shared__ float arow[8][S_];
    __shared__ float wred[8];
    __shared__ int wcnt[8], cand[8];

    s_l[t]  = scores[b * S_ + t];
    qs_l[t] = q_state[b * S_ + t];
    if (END) us_l[t] = u_s[b * S_ + t];
    __syncthreads();

    int cnt = select_cands(s_l, t, lane, w, wred, wcnt, cand);

    for (int c = 0; c < cnt; ++c)
        arow[c][t] = support[((size_t)(b * LS_ + cand[c])) * S_ + t];
    __syncthreads();

    if (w < cnt) {
        int s0 = chunk * 128 + lane, s1 = s0 + 64;
        float z0 = inter[b * S_ + s0], z1 = inter[b * S_ + s1];
        const float* W1 = Wbig;
        const float* W2 = Wbig + (size_t)S_ * S_;
        const float* W3 = Wbig + (size_t)2 * S_ * S_;
        #pragma unroll 4
        for (int d = 0; d < S_; ++d) {
            float a = arow[w][d];
            float qa = qs_l[d] * a;
            const float* r1 = W1 + (size_t)d * S_;
            const float* r2 = W2 + (size_t)d * S_;
            if (END) {
                float ua = us_l[d] * a;
                const float* r3 = W3 + (size_t)d * S_;
                z0 = fmaf(ua, r1[s0], fmaf(qa, r2[s0], fmaf(a, r3[s0], z0)));
                z1 = fmaf(ua, r1[s1], fmaf(qa, r2[s1], fmaf(a, r3[s1], z1)));
            } else {
                z0 = fmaf(qa, r1[s0], fmaf(a, r2[s0], z0));
                z1 = fmaf(qa, r1[s1], fmaf(a, r2[s1], z1));
            }
        }
        float p = fmaxf(z0, 0.f) * Wsmall[s0] + fmaxf(z1, 0.f) * Wsmall[s1];
        #pragma unroll
        for (int off = 32; off >= 1; off >>= 1)
            p += __shfl_xor(p, off);
        if (lane == 0) part[((size_t)b * 8 + w) * 4 + chunk] = p;
    }
}

// ---------------- Kernel F: finalize (exact argmax, sp/u_s/pred) ----------
template <bool END>
__global__ __launch_bounds__(512)
void finalize_kernel(const float* __restrict__ scores, const float* __restrict__ part,
                     const float* __restrict__ support, int* __restrict__ sp_ws,
                     float* __restrict__ pred, float* __restrict__ us_out)
{
    int b = blockIdx.x;
    int t = threadIdx.x, lane = t & 63, w = t >> 6;
    __shared__ float s_l[S_];
    __shared__ float wred[8];
    __shared__ int wcnt[8], cand[8];
    __shared__ int best_sh;

    s_l[t] = scores[b * S_ + t];
    __syncthreads();
    int cnt = select_cands(s_l, t, lane, w, wred, wcnt, cand);

    if (t == 0) {
        float bv = -INFINITY;
        int bi = cand[0];
        for (int c = 0; c < cnt; ++c) {
            const float* pp = part + ((size_t)b * 8 + c) * 4;
            float e = ((pp[0] + pp[1]) + pp[2]) + pp[3];
            if (e > bv) { bv = e; bi = cand[c]; }
        }
        best_sh = bi;
        pred[b] = (float)bi;
        if (!END) sp_ws[b] = bi;
    }
    __syncthreads();
    if (!END)
        us_out[b * S_ + t] = support[((size_t)(b * LS_ + best_sh)) * S_ + t];
}

// ---------------- launch ----------------
extern "C" void kernel_launch(void* const* d_in, const int* in_sizes, int n_in,
                              void* d_out, int out_size, void* d_ws, size_t ws_size,
                              hipStream_t stream)
{
    const float* eq    = (const float*)d_in[0];
    const float* es    = (const float*)d_in[1];
    const int*   qlen  = (const int*)d_in[2];
    const int*   slen  = (const int*)d_in[3];
    const float* W_qa  = (const float*)d_in[7];
    const float* W_qsi = (const float*)d_in[8];
    const float* b_qsi = (const float*)d_in[9];
    const float* W_qs  = (const float*)d_in[10];
    const float* W_ss  = (const float*)d_in[11];
    const float* W_qei = (const float*)d_in[12];
    const float* b_qei = (const float*)d_in[13];
    const float* W_qe  = (const float*)d_in[14];
    const float* W_es  = (const float*)d_in[15];

    float* out          = (float*)d_out;
    float* start_scores = out;
    float* end_scores   = out + B_ * LS_;
    float* pred_start   = out + 2 * B_ * LS_;
    float* pred_end     = out + 2 * B_ * LS_ + B_;

    float* ws      = (float*)d_ws;
    float* q_state = ws;                       // [B,S]
    float* qsi     = ws + B_ * S_;             // [B,S]
    float* qei     = ws + 2 * B_ * S_;         // [B,S]
    float* u_s     = ws + 3 * B_ * S_;         // [B,S]
    float* part    = ws + 4 * B_ * S_;         // [B,8,4]
    int*   sp_ws   = (int*)(ws + 4 * B_ * S_ + 2048);   // [B]
    short* Wc      = (short*)(ws + 4 * B_ * S_ + 2048 + 512); // 16.78M shorts = 33.5 MB

    qpool_kernel<<<B_, 256, 0, stream>>>(eq, qlen, W_qa, q_state);
    inter_kernel<<<dim3(B_, 2), 256, 0, stream>>>(q_state, W_qsi, b_qsi, W_qei, b_qei, qsi, qei);

    // ---- start pass ----
    prep_kernel<2><<<1024, 512, 0, stream>>>(W_qs, q_state, nullptr, Wc);
    score_kernel<false><<<512, 512, 0, stream>>>(es, Wc, qsi, W_ss, slen, nullptr, start_scores);
    rescue_kernel<false><<<256, 512, 0, stream>>>(es, q_state, nullptr, W_qs, qsi, W_ss,
                                                  start_scores, part);
    finalize_kernel<false><<<B_, 512, 0, stream>>>(start_scores, part, es, sp_ws, pred_start, u_s);

    // ---- end pass ----
    prep_kernel<3><<<1024, 512, 0, stream>>>(W_qe, q_state, u_s, Wc);
    score_kernel<true><<<512, 512, 0, stream>>>(es, Wc, qei, W_es, slen, sp_ws, end_scores);
    rescue_kernel<true><<<256, 512, 0, stream>>>(es, q_state, u_s, W_qe, qei, W_es,
                                                 end_scores, part);
    finalize_kernel<true><<<B_, 512, 0, stream>>>(end_scores, part, es, nullptr, pred_end, nullptr);
}

// Round 6
// 169.588 us; speedup vs baseline: 6.5135x; 1.4997x over previous
//
#include <hip/hip_runtime.h>
#include <math.h>

constexpr int B_  = 64;
constexpr int LQ_ = 64;
constexpr int LS_ = 512;
constexpr int S_  = 512;
#define NEGV (-1e6f)
#define MARGIN 0.0625f

typedef __attribute__((ext_vector_type(8))) short bf16x8;
typedef __attribute__((ext_vector_type(4))) float f32x4;

__device__ inline unsigned short f2bf_rn(float x) {
    unsigned u = __builtin_bit_cast(unsigned, x);
    unsigned r = (u + 0x7FFFu + ((u >> 16) & 1u)) >> 16;
    return (unsigned short)r;
}

// ---------------- Kernel 1: question attention pooling ----------------
__global__ __launch_bounds__(256)
void qpool_kernel(const float* __restrict__ eq, const int* __restrict__ qlen,
                  const float* __restrict__ W_qa, float* __restrict__ q_state)
{
    int b = blockIdx.x;
    int t = threadIdx.x;
    int wave = t >> 6, lane = t & 63;
    __shared__ float att[LQ_];
    __shared__ float wsm[LQ_];
    const float* eqb = eq + (size_t)b * LQ_ * S_;

    for (int k = 0; k < 16; ++k) {
        int q = wave + 4 * k;
        const float* row = eqb + q * S_;
        float s = 0.f;
        #pragma unroll
        for (int j = 0; j < S_ / 64; ++j)
            s = fmaf(row[lane + 64 * j], W_qa[lane + 64 * j], s);
        #pragma unroll
        for (int off = 32; off >= 1; off >>= 1)
            s += __shfl_xor(s, off);
        if (lane == 0) att[q] = s;
    }
    __syncthreads();

    if (wave == 0) {
        int L = qlen[b];
        float v = att[lane] + ((lane < L) ? 0.f : NEGV);
        float m = v;
        #pragma unroll
        for (int off = 32; off >= 1; off >>= 1)
            m = fmaxf(m, __shfl_xor(m, off));
        float e = expf(v - m);
        float sum = e;
        #pragma unroll
        for (int off = 32; off >= 1; off >>= 1)
            sum += __shfl_xor(sum, off);
        wsm[lane] = e / sum;
    }
    __syncthreads();

    for (int d = t; d < S_; d += 256) {
        float acc = 0.f;
        #pragma unroll 8
        for (int q = 0; q < LQ_; ++q)
            acc = fmaf(wsm[q], eqb[q * S_ + d], acc);
        q_state[b * S_ + d] = acc;
    }
}

// ---------------- Kernel 2: q_start_inter / q_end_inter (f32 exact) --------
// waves split the d-dimension (64 each), LDS cross-wave reduce.
__global__ __launch_bounds__(512)
void inter_kernel(const float* __restrict__ q_state,
                  const float* __restrict__ W_qsi, const float* __restrict__ b_qsi,
                  const float* __restrict__ W_qei, const float* __restrict__ b_qei,
                  float* __restrict__ qsi, float* __restrict__ qei)
{
    int b = blockIdx.x;
    const float* W  = blockIdx.y ? W_qei : W_qsi;
    const float* bi = blockIdx.y ? b_qei : b_qsi;
    float*       o  = blockIdx.y ? qei   : qsi;
    int t = threadIdx.x, lane = t & 63, w = t >> 6;
    __shared__ float qs[S_];
    __shared__ float red[8][S_];
    qs[t] = q_state[b * S_ + t];
    __syncthreads();

    float z[8];
    #pragma unroll
    for (int k = 0; k < 8; ++k) z[k] = 0.f;
    const int d0 = w * 64;
    #pragma unroll 4
    for (int dd = 0; dd < 64; ++dd) {
        int d = d0 + dd;
        float q = qs[d];
        const float* row = W + (size_t)d * S_ + lane;
        #pragma unroll
        for (int k = 0; k < 8; ++k)
            z[k] = fmaf(q, row[k * 64], z[k]);
    }
    #pragma unroll
    for (int k = 0; k < 8; ++k) red[w][k * 64 + lane] = z[k];
    __syncthreads();
    float acc = bi[t];
    #pragma unroll
    for (int ww = 0; ww < 8; ++ww) acc += red[ww][t];
    o[b * S_ + t] = acc;
}

// ---------------- Kernel P: per-batch folded weight prep (bf16 hi) ---------
template <int NT>
__global__ __launch_bounds__(512)
void prep_kernel(const float* __restrict__ W, const float* __restrict__ q_state,
                 const float* __restrict__ u_s, short* __restrict__ Wc)
{
    int bid = blockIdx.x;
    int i = bid >> 6, b = bid & 63;     // 64 consecutive blocks share W slice (L2)
    int col = threadIdx.x;
    __shared__ float scq[32], scu[32];
    if (col < 32) scq[col] = q_state[b * S_ + i * 32 + col];
    if (NT == 3 && col >= 32 && col < 64) scu[col - 32] = u_s[b * S_ + i * 32 + col - 32];
    __syncthreads();

    unsigned short h[32];
    #pragma unroll
    for (int d = 0; d < 32; ++d) {
        int D = i * 32 + d;
        float v;
        if (NT == 2)
            v = fmaf(scq[d], W[(size_t)D * S_ + col], W[(size_t)(S_ + D) * S_ + col]);
        else
            v = fmaf(scu[d], W[(size_t)D * S_ + col],
                fmaf(scq[d], W[(size_t)(S_ + D) * S_ + col], W[(size_t)(2 * S_ + D) * S_ + col]));
        h[d] = f2bf_rn(v);
    }
    size_t base = (size_t)b * 262144 + (size_t)i * 16384 + (size_t)col * 8;
    #pragma unroll
    for (int kc = 0; kc < 4; ++kc) {
        uint4 H;
        H.x = h[kc*8+0] | ((unsigned)h[kc*8+1] << 16);
        H.y = h[kc*8+2] | ((unsigned)h[kc*8+3] << 16);
        H.z = h[kc*8+4] | ((unsigned)h[kc*8+5] << 16);
        H.w = h[kc*8+6] | ((unsigned)h[kc*8+7] << 16);
        *(uint4*)&Wc[base + kc * 4096] = H;
    }
}

// ---------------- Kernel S: folded 1-term bf16 MFMA score ----------------
template <bool END>
__global__ __launch_bounds__(512, 4)
void score_kernel(const float* __restrict__ support, const short* __restrict__ Wc,
                  const float* __restrict__ inter, const float* __restrict__ Wsmall,
                  const int* __restrict__ slen, const int* __restrict__ sp,
                  float* __restrict__ out)
{
    const int t = threadIdx.x;
    const int lane = t & 63, wid = t >> 6;
    const int l15 = lane & 15, l4 = lane >> 4;

    int L = blockIdx.x;
    int xcd = L & 7, idx = L >> 3;
    int b = xcd * 8 + (idx & 7);
    int rc = idx >> 3;
    int l0 = rc * 64;

    __shared__ __attribute__((aligned(16))) short Bs[2][4][512][8];  // 64 KB
    __shared__ __attribute__((aligned(16))) short As[2][4][64][8];   // 8 KB
    __shared__ float int_l[S_], wsm_l[S_];
    __shared__ float sm_red[64][8];

    int_l[t] = inter[b * S_ + t];
    wsm_l[t] = Wsmall[t];

    const char* wc_bytes = (const char*)(Wc + (size_t)b * 262144);

    const int arow = t >> 3;
    const int akc  = (t >> 1) & 3;
    const int ahalf = t & 1;
    const float* supb = support + ((size_t)(b * LS_ + l0 + arow)) * S_ + akc * 8 + ahalf * 4;

    f32x4 acc[4][4];
    #pragma unroll
    for (int r = 0; r < 4; ++r)
        #pragma unroll
        for (int c = 0; c < 4; ++c)
            acc[r][c] = (f32x4){0.f, 0.f, 0.f, 0.f};

    auto stage = [&](int i, int pbuf) {
        const char* gb = wc_bytes + (size_t)i * 32768 + t * 16;
        char* lb = (char*)&Bs[pbuf][0][0][0] + t * 16;
        #pragma unroll
        for (int q = 0; q < 4; ++q)
            __builtin_amdgcn_global_load_lds(
                (const __attribute__((address_space(1))) void*)(gb + q * 8192),
                (__attribute__((address_space(3))) void*)(lb + q * 8192), 16, 0, 0);
    };
    auto buildA = [&](int pbuf, float4 v) {
        unsigned short h0 = f2bf_rn(v.x), h1 = f2bf_rn(v.y);
        unsigned short h2 = f2bf_rn(v.z), h3 = f2bf_rn(v.w);
        uint2 P;
        P.x = h0 | ((unsigned)h1 << 16);
        P.y = h2 | ((unsigned)h3 << 16);
        *(uint2*)&As[pbuf][akc][arow][ahalf * 4] = P;
    };

    float4 sv = *(const float4*)(supb);
    buildA(0, sv);
    stage(0, 0);
    float4 svn = *(const float4*)(supb + 32);

    for (int i = 0; i < 16; ++i) {
        const int par = i & 1;
        if (i + 1 < 16) {
            stage(i + 1, par ^ 1);
            buildA(par ^ 1, svn);
            if (i + 2 < 16) svn = *(const float4*)(supb + (i + 2) * 32);
            asm volatile("s_waitcnt vmcnt(5) lgkmcnt(0)" ::: "memory");
        } else {
            asm volatile("s_waitcnt vmcnt(0) lgkmcnt(0)" ::: "memory");
        }
        __builtin_amdgcn_s_barrier();

        bf16x8 ah[4];
        #pragma unroll
        for (int r = 0; r < 4; ++r)
            ah[r] = *(const bf16x8*)&As[par][l4][r * 16 + l15][0];
        #pragma unroll
        for (int c = 0; c < 4; ++c) {
            bf16x8 bh = *(const bf16x8*)&Bs[par][l4][wid * 64 + c * 16 + l15][0];
            #pragma unroll
            for (int r = 0; r < 4; ++r)
                acc[r][c] = __builtin_amdgcn_mfma_f32_16x16x32_bf16(ah[r], bh, acc[r][c], 0, 0, 0);
        }
        asm volatile("s_waitcnt lgkmcnt(0)" ::: "memory");
        __builtin_amdgcn_s_barrier();
    }

    #pragma unroll
    for (int r = 0; r < 4; ++r) {
        #pragma unroll
        for (int jj = 0; jj < 4; ++jj) {
            float pr = 0.f;
            #pragma unroll
            for (int c = 0; c < 4; ++c) {
                int col = wid * 64 + c * 16 + l15;
                float v = acc[r][c][jj] + int_l[col];
                v = fmaxf(v, 0.f);
                pr = fmaf(v, wsm_l[col], pr);
            }
            pr += __shfl_xor(pr, 1);
            pr += __shfl_xor(pr, 2);
            pr += __shfl_xor(pr, 4);
            pr += __shfl_xor(pr, 8);
            if (l15 == 0) sm_red[r * 16 + l4 * 4 + jj][wid] = pr;
        }
    }
    __syncthreads();
    if (t < 64) {
        int l = l0 + t;
        float s = 0.f;
        #pragma unroll
        for (int w = 0; w < 8; ++w) s += sm_red[t][w];
        if (l >= slen[b]) s += NEGV;
        if (END) { if (l < sp[b]) s += NEGV; }
        out[b * LS_ + l] = s;
    }
}

// ---------------- candidate selection (shared by rescue/finalize) ----------
__device__ inline int select_cands(const float* s_l, int t, int lane, int w,
                                   float* wred, int* wcnt, int* cand)
{
    float v = s_l[t];
    #pragma unroll
    for (int off = 32; off >= 1; off >>= 1)
        v = fmaxf(v, __shfl_xor(v, off));
    if (lane == 0) wred[w] = v;
    __syncthreads();
    float m = wred[0];
    #pragma unroll
    for (int k = 1; k < 8; ++k) m = fmaxf(m, wred[k]);
    float th = m - MARGIN;
    bool flag = s_l[t] >= th;
    unsigned long long bal = __ballot(flag);
    int rank = __popcll(bal & ((1ull << lane) - 1ull));
    if (lane == 0) wcnt[w] = (int)__popcll(bal);
    __syncthreads();
    int off = 0, total = 0;
    #pragma unroll
    for (int k = 0; k < 8; ++k) { if (k < w) off += wcnt[k]; total += wcnt[k]; }
    if (flag) { int pos = off + rank; if (pos < 8) cand[pos] = t; }
    __syncthreads();
    return total < 8 ? total : 8;
}

// ---------------- Kernel R: exact f32 rescue, wave-parallel over d ----------
// Block (b, chunk): 128 columns. Wave w owns d-slice [64w,64w+64); lane owns
// cols {chunk*128+lane, +64}. All 8 candidate slots accumulated in registers
// (W loads shared across candidates). LDS cross-wave reduce; wave c finishes
// candidate c.
template <bool END>
__global__ __launch_bounds__(512)
void rescue_kernel(const float* __restrict__ support, const float* __restrict__ q_state,
                   const float* __restrict__ u_s, const float* __restrict__ Wbig,
                   const float* __restrict__ inter, const float* __restrict__ Wsmall,
                   const float* __restrict__ scores, float* __restrict__ part)
{
    int bid = blockIdx.x;
    int b = bid >> 2, chunk = bid & 3;
    int t = threadIdx.x, lane = t & 63, w = t >> 6;
    __shared__ float s_l[S_], qs_l[S_], us_l[S_];
    __shared__ float arow[8][S_];
    __shared__ float red[8][8][128];   // [wave][cand][col-in-chunk]
    __shared__ float wred[8];
    __shared__ int wcnt[8], cand[8];

    s_l[t]  = scores[b * S_ + t];
    qs_l[t] = q_state[b * S_ + t];
    if (END) us_l[t] = u_s[b * S_ + t];
    #pragma unroll
    for (int c = 0; c < 8; ++c) arow[c][t] = 0.f;
    __syncthreads();

    int cnt = select_cands(s_l, t, lane, w, wred, wcnt, cand);

    for (int c = 0; c < cnt; ++c)
        arow[c][t] = support[((size_t)(b * LS_ + cand[c])) * S_ + t];
    __syncthreads();

    float z0[8], z1[8];
    #pragma unroll
    for (int c = 0; c < 8; ++c) { z0[c] = 0.f; z1[c] = 0.f; }

    const int d0 = w * 64;
    const int s0 = chunk * 128 + lane, s1 = s0 + 64;
    const float* W1 = Wbig;
    const float* W2 = Wbig + (size_t)S_ * S_;
    const float* W3 = Wbig + (size_t)2 * S_ * S_;

    #pragma unroll 4
    for (int dd = 0; dd < 64; ++dd) {
        int d = d0 + dd;
        float r1a = W1[(size_t)d * S_ + s0], r1b = W1[(size_t)d * S_ + s1];
        float r2a = W2[(size_t)d * S_ + s0], r2b = W2[(size_t)d * S_ + s1];
        float r3a = 0.f, r3b = 0.f;
        if (END) { r3a = W3[(size_t)d * S_ + s0]; r3b = W3[(size_t)d * S_ + s1]; }
        float q = qs_l[d];
        float u = END ? us_l[d] : 0.f;
        #pragma unroll
        for (int c = 0; c < 8; ++c) {
            float a = arow[c][d];
            if (END) {
                float ua = u * a, qa = q * a;
                z0[c] = fmaf(ua, r1a, fmaf(qa, r2a, fmaf(a, r3a, z0[c])));
                z1[c] = fmaf(ua, r1b, fmaf(qa, r2b, fmaf(a, r3b, z1[c])));
            } else {
                float qa = q * a;
                z0[c] = fmaf(qa, r1a, fmaf(a, r2a, z0[c]));
                z1[c] = fmaf(qa, r1b, fmaf(a, r2b, z1[c]));
            }
        }
    }
    #pragma unroll
    for (int c = 0; c < 8; ++c) {
        red[w][c][lane]      = z0[c];
        red[w][c][64 + lane] = z1[c];
    }
    __syncthreads();

    // wave w finalizes candidate slot w over this chunk's 128 columns
    {
        float a0 = 0.f, a1 = 0.f;
        #pragma unroll
        for (int ww = 0; ww < 8; ++ww) {
            a0 += red[ww][w][lane];
            a1 += red[ww][w][64 + lane];
        }
        float v0 = fmaxf(a0 + inter[b * S_ + s0], 0.f) * Wsmall[s0];
        float v1 = fmaxf(a1 + inter[b * S_ + s1], 0.f) * Wsmall[s1];
        float p = v0 + v1;
        #pragma unroll
        for (int off = 32; off >= 1; off >>= 1)
            p += __shfl_xor(p, off);
        if (lane == 0 && w < cnt) part[((size_t)b * 8 + w) * 4 + chunk] = p;
    }
}

// ---------------- Kernel F: finalize (exact argmax, sp/u_s/pred) ----------
template <bool END>
__global__ __launch_bounds__(512)
void finalize_kernel(const float* __restrict__ scores, const float* __restrict__ part,
                     const float* __restrict__ support, int* __restrict__ sp_ws,
                     float* __restrict__ pred, float* __restrict__ us_out)
{
    int b = blockIdx.x;
    int t = threadIdx.x, lane = t & 63, w = t >> 6;
    __shared__ float s_l[S_];
    __shared__ float wred[8];
    __shared__ int wcnt[8], cand[8];
    __shared__ int best_sh;

    s_l[t] = scores[b * S_ + t];
    __syncthreads();
    int cnt = select_cands(s_l, t, lane, w, wred, wcnt, cand);

    if (t == 0) {
        float bv = -INFINITY;
        int bi = cand[0];
        for (int c = 0; c < cnt; ++c) {
            const float* pp = part + ((size_t)b * 8 + c) * 4;
            float e = ((pp[0] + pp[1]) + pp[2]) + pp[3];
            if (e > bv) { bv = e; bi = cand[c]; }
        }
        best_sh = bi;
        pred[b] = (float)bi;
        if (!END) sp_ws[b] = bi;
    }
    __syncthreads();
    if (!END)
        us_out[b * S_ + t] = support[((size_t)(b * LS_ + best_sh)) * S_ + t];
}

// ---------------- launch ----------------
extern "C" void kernel_launch(void* const* d_in, const int* in_sizes, int n_in,
                              void* d_out, int out_size, void* d_ws, size_t ws_size,
                              hipStream_t stream)
{
    const float* eq    = (const float*)d_in[0];
    const float* es    = (const float*)d_in[1];
    const int*   qlen  = (const int*)d_in[2];
    const int*   slen  = (const int*)d_in[3];
    const float* W_qa  = (const float*)d_in[7];
    const float* W_qsi = (const float*)d_in[8];
    const float* b_qsi = (const float*)d_in[9];
    const float* W_qs  = (const float*)d_in[10];
    const float* W_ss  = (const float*)d_in[11];
    const float* W_qei = (const float*)d_in[12];
    const float* b_qei = (const float*)d_in[13];
    const float* W_qe  = (const float*)d_in[14];
    const float* W_es  = (const float*)d_in[15];

    float* out          = (float*)d_out;
    float* start_scores = out;
    float* end_scores   = out + B_ * LS_;
    float* pred_start   = out + 2 * B_ * LS_;
    float* pred_end     = out + 2 * B_ * LS_ + B_;

    float* ws      = (float*)d_ws;
    float* q_state = ws;                       // [B,S]
    float* qsi     = ws + B_ * S_;             // [B,S]
    float* qei     = ws + 2 * B_ * S_;         // [B,S]
    float* u_s     = ws + 3 * B_ * S_;         // [B,S]
    float* part    = ws + 4 * B_ * S_;         // [B,8,4]
    int*   sp_ws   = (int*)(ws + 4 * B_ * S_ + 2048);   // [B]
    short* Wc      = (short*)(ws + 4 * B_ * S_ + 2048 + 512); // 33.5 MB

    qpool_kernel<<<B_, 256, 0, stream>>>(eq, qlen, W_qa, q_state);
    inter_kernel<<<dim3(B_, 2), 512, 0, stream>>>(q_state, W_qsi, b_qsi, W_qei, b_qei, qsi, qei);

    // ---- start pass ----
    prep_kernel<2><<<1024, 512, 0, stream>>>(W_qs, q_state, nullptr, Wc);
    score_kernel<false><<<512, 512, 0, stream>>>(es, Wc, qsi, W_ss, slen, nullptr, start_scores);
    rescue_kernel<false><<<256, 512, 0, stream>>>(es, q_state, nullptr, W_qs, qsi, W_ss,
                                                  start_scores, part);
    finalize_kernel<false><<<B_, 512, 0, stream>>>(start_scores, part, es, sp_ws, pred_start, u_s);

    // ---- end pass ----
    prep_kernel<3><<<1024, 512, 0, stream>>>(W_qe, q_state, u_s, Wc);
    score_kernel<true><<<512, 512, 0, stream>>>(es, Wc, qei, W_es, slen, sp_ws, end_scores);
    rescue_kernel<true><<<256, 512, 0, stream>>>(es, q_state, u_s, W_qe, qei, W_es,
                                                 end_scores, part);
    finalize_kernel<true><<<B_, 512, 0, stream>>>(end_scores, part, es, nullptr, pred_end, nullptr);
}